// Round 2
// baseline (729.070 us; speedup 1.0000x reference)
//
#include <hip/hip_runtime.h>
#include <stdint.h>

#define NB 131072      // src bins (src < 100000 < 2^17)
#define LMAX 1024      // per-bin LDS sort capacity (max bin len ~130 at mean 49)

__device__ __forceinline__ uint32_t rotl32(uint32_t x, int r) { return (x << r) | (x >> (32 - r)); }

// JAX threefry2x32 with key=(0,42), counts x=(0,i); partitionable bits = out0^out1
__device__ __forceinline__ uint32_t threefry_bits(uint32_t i) {
  const uint32_t k0 = 0u, k1 = 42u;
  const uint32_t k2 = k0 ^ k1 ^ 0x1BD11BDAu;
  uint32_t x0 = k0;       // 0 + k0
  uint32_t x1 = i + k1;
#define TF_R(r) { x0 += x1; x1 = rotl32(x1, r); x1 ^= x0; }
  TF_R(13) TF_R(15) TF_R(26) TF_R(6)   x0 += k1; x1 += k2 + 1u;
  TF_R(17) TF_R(29) TF_R(16) TF_R(24)  x0 += k2; x1 += k0 + 2u;
  TF_R(13) TF_R(15) TF_R(26) TF_R(6)   x0 += k0; x1 += k1 + 3u;
  TF_R(17) TF_R(29) TF_R(16) TF_R(24)  x0 += k1; x1 += k2 + 4u;
  TF_R(13) TF_R(15) TF_R(26) TF_R(6)   x0 += k2; x1 += k0 + 5u;
#undef TF_R
  return x0 ^ x1;
}

__device__ __forceinline__ bool keep_edge(uint32_t i, float kp) {
  uint32_t bits = threefry_bits(i);
  float u = __uint_as_float((bits >> 9) | 0x3f800000u) - 1.0f;  // multiples of 2^-23, exact
  return u < kp;
}

__device__ __forceinline__ float keep_prob(const float* pp) {
  double pd = (double)pp[0];
  return (float)(1.0 / (1.0 + exp(-pd)));  // f32-rounded; +1ulp-robust at compare boundary
}

// ---- pass 1: histogram of src bins (kept A0 edges + all An edges) ----
__global__ void hist_k(const int* __restrict__ a0, const int* __restrict__ an,
                       int e0, int en, const float* __restrict__ pp,
                       uint32_t* __restrict__ cnt) {
  float kp = keep_prob(pp);
  int total = e0 + en;
  for (int idx = blockIdx.x * blockDim.x + threadIdx.x; idx < total;
       idx += gridDim.x * blockDim.x) {
    int s;
    if (idx < e0) {
      if (!keep_edge((uint32_t)idx, kp)) continue;
      s = a0[idx];
    } else {
      s = an[idx - e0];
    }
    if ((unsigned)s < NB) atomicAdd(&cnt[s], 1u);
  }
}

// ---- exclusive scan over NB bins: 3 kernels ----
__global__ void scan1_k(const uint32_t* __restrict__ in, uint32_t* __restrict__ out,
                        uint32_t* __restrict__ bsums, int n) {
  __shared__ uint32_t tmp[256];
  int t = threadIdx.x;
  int i = blockIdx.x * 256 + t;
  uint32_t v = (i < n) ? in[i] : 0u;
  tmp[t] = v;
  __syncthreads();
  for (int off = 1; off < 256; off <<= 1) {
    uint32_t add = (t >= off) ? tmp[t - off] : 0u;
    __syncthreads();
    tmp[t] += add;
    __syncthreads();
  }
  uint32_t incl = tmp[t];
  if (i < n) out[i] = incl - v;            // exclusive
  if (t == 255) bsums[blockIdx.x] = incl;  // block total
}

__global__ void scan2_k(uint32_t* __restrict__ bsums, int nb) {
  __shared__ uint32_t tmp[512];
  int t = threadIdx.x;
  uint32_t v = (t < nb) ? bsums[t] : 0u;
  tmp[t] = v;
  __syncthreads();
  for (int off = 1; off < 512; off <<= 1) {
    uint32_t add = (t >= off) ? tmp[t - off] : 0u;
    __syncthreads();
    tmp[t] += add;
    __syncthreads();
  }
  if (t < nb) bsums[t] = tmp[t] - v;  // exclusive
}

__global__ void scan3_k(uint32_t* __restrict__ out, const uint32_t* __restrict__ in,
                        const uint32_t* __restrict__ bsums, int n) {
  int i = blockIdx.x * 256 + threadIdx.x;
  if (i < n) {
    uint32_t v = out[i] + bsums[blockIdx.x];
    out[i] = v;
    if (i == n - 1) out[n] = v + in[i];  // grand total at out[n]
  }
}

// ---- pass 2: scatter dst values into per-src segments ----
__global__ void scatter_k(const int* __restrict__ a0, const int* __restrict__ an,
                          int e0, int en, const float* __restrict__ pp,
                          uint32_t* __restrict__ cur, uint32_t* __restrict__ dst1) {
  float kp = keep_prob(pp);
  int total = e0 + en;
  for (int idx = blockIdx.x * blockDim.x + threadIdx.x; idx < total;
       idx += gridDim.x * blockDim.x) {
    int s, d;
    if (idx < e0) {
      if (!keep_edge((uint32_t)idx, kp)) continue;
      s = a0[idx];
      d = a0[e0 + idx];
    } else {
      int j = idx - e0;
      s = an[j];
      d = an[en + j];
    }
    if ((unsigned)s < NB) {
      uint32_t pos = atomicAdd(&cur[s], 1u);
      dst1[pos] = (uint32_t)d;
    }
  }
}

// ---- pass 3: per-bin rank sort + dedup-compact, all in LDS (one wave per bin) ----
__global__ __launch_bounds__(64) void segsort_k(uint32_t* __restrict__ dst1,
                                                uint32_t* __restrict__ dst2,
                                                const uint32_t* __restrict__ off,
                                                uint32_t* __restrict__ ucnt) {
  int b = blockIdx.x;
  uint32_t s = off[b], e = off[b + 1];
  int len = (int)(e - s);
  if (len == 0) {
    if (threadIdx.x == 0) ucnt[b] = 0u;
    return;
  }
  __shared__ uint32_t lin[LMAX];
  __shared__ uint32_t lsort[LMAX];
  if (len <= LMAX) {
    // load into LDS
    for (int i = threadIdx.x; i < len; i += 64) lin[i] = dst1[s + i];
    __syncthreads();
    // rank sort (stable via index tie-break) into lsort
    for (int base = 0; base < len; base += 64) {
      int i = base + threadIdx.x;
      if (i < len) {
        uint32_t x = lin[i];
        int pos = 0;
        for (int j = 0; j < len; j++) {
          uint32_t y = lin[j];  // uniform read -> LDS broadcast, conflict-free
          pos += (y < x || (y == x && j < i)) ? 1 : 0;
        }
        lsort[pos] = x;
      }
    }
    __syncthreads();
    // dedup: keep first of each run, compact back into dst1[s..]
    uint32_t uidx = 0;
    for (int base = 0; base < len; base += 64) {
      int i = base + threadIdx.x;
      bool valid = (i < len);
      uint32_t x = valid ? lsort[i] : 0u;
      bool uniq = valid && (i == 0 || lsort[i - 1] != x);
      unsigned long long ball = __ballot(uniq ? 1 : 0);
      unsigned long long ltmask = (1ull << threadIdx.x) - 1ull;
      int before = __popcll(ball & ltmask);
      if (uniq) dst1[s + uidx + (uint32_t)before] = x;
      uidx += (uint32_t)__popcll(ball);
    }
    if (threadIdx.x == 0) ucnt[b] = uidx;
  } else {
    // fallback for oversized bins (not expected at this distribution): global rank sort
    for (int base = 0; base < len; base += 64) {
      int i = base + threadIdx.x;
      if (i < len) {
        uint32_t x = dst1[s + i];
        int pos = 0;
        for (int j = 0; j < len; j++) {
          uint32_t y = dst1[s + j];
          pos += (y < x || (y == x && j < i)) ? 1 : 0;
        }
        dst2[s + (uint32_t)pos] = x;
      }
    }
    __syncthreads();
    uint32_t uidx = 0;
    for (int base = 0; base < len; base += 64) {
      int i = base + threadIdx.x;
      bool valid = (i < len);
      uint32_t x = valid ? dst2[s + i] : 0u;
      bool uniq = valid && (i == 0 || dst2[s + i - 1] != x);
      unsigned long long ball = __ballot(uniq ? 1 : 0);
      unsigned long long ltmask = (1ull << threadIdx.x) - 1ull;
      int before = __popcll(ball & ltmask);
      if (uniq) dst1[s + uidx + (uint32_t)before] = x;
      uidx += (uint32_t)__popcll(ball);
    }
    if (threadIdx.x == 0) ucnt[b] = uidx;
  }
}

// ---- fill output with -1 ----
__global__ void fill_k(int* __restrict__ out, int n) {
  for (int i = blockIdx.x * blockDim.x + threadIdx.x; i < n;
       i += gridDim.x * blockDim.x)
    out[i] = -1;
}

// ---- pass 4: write unique (src,dst) at global offsets ----
__global__ __launch_bounds__(64) void outscatter_k(const uint32_t* __restrict__ dst1,
                                                   const uint32_t* __restrict__ off,
                                                   const uint32_t* __restrict__ uoff,
                                                   const uint32_t* __restrict__ ucnt,
                                                   int* __restrict__ out, int oute) {
  int b = blockIdx.x;
  uint32_t u = ucnt[b];
  if (u == 0) return;
  uint32_t s = off[b];
  uint32_t base = uoff[b];
  for (uint32_t k = threadIdx.x; k < u; k += 64) {
    out[base + k] = b;                         // src row
    out[oute + base + k] = (int)dst1[s + k];   // dst row
  }
}

extern "C" void kernel_launch(void* const* d_in, const int* in_sizes, int n_in,
                              void* d_out, int out_size, void* d_ws, size_t ws_size,
                              hipStream_t stream) {
  const int* a0 = (const int*)d_in[0];
  const int* an = (const int*)d_in[1];
  const float* pp = (const float*)d_in[3];
  int e0 = in_sizes[0] / 2;
  int en = in_sizes[1] / 2;
  int M = e0 + en;
  int oute = out_size / 2;

  // workspace layout (256B aligned slices); total ~28 MB
  uint8_t* base = (uint8_t*)d_ws;
  size_t o = 0;
  auto nxt = [&](size_t bytes) -> void* {
    void* p = base + o;
    o = (o + bytes + 255) & ~(size_t)255;
    return p;
  };
  uint32_t* cnt  = (uint32_t*)nxt((size_t)NB * 4);
  uint32_t* off  = (uint32_t*)nxt((size_t)(NB + 1) * 4);
  uint32_t* cur  = (uint32_t*)nxt((size_t)NB * 4);
  uint32_t* ucnt = (uint32_t*)nxt((size_t)NB * 4);
  uint32_t* uoff = (uint32_t*)nxt((size_t)(NB + 1) * 4);
  uint32_t* bs   = (uint32_t*)nxt((size_t)512 * 4);
  uint32_t* dst1 = (uint32_t*)nxt((size_t)M * 4);
  uint32_t* dst2 = (uint32_t*)d_out;  // fallback-path scratch only; overwritten by fill_k

  const int SCAN_BLOCKS = NB / 256;  // 512

  hipMemsetAsync(cnt, 0, (size_t)NB * 4, stream);
  hist_k<<<2048, 256, 0, stream>>>(a0, an, e0, en, pp, cnt);

  scan1_k<<<SCAN_BLOCKS, 256, 0, stream>>>(cnt, off, bs, NB);
  scan2_k<<<1, 512, 0, stream>>>(bs, SCAN_BLOCKS);
  scan3_k<<<SCAN_BLOCKS, 256, 0, stream>>>(off, cnt, bs, NB);

  hipMemcpyAsync(cur, off, (size_t)NB * 4, hipMemcpyDeviceToDevice, stream);
  scatter_k<<<2048, 256, 0, stream>>>(a0, an, e0, en, pp, cur, dst1);

  segsort_k<<<NB, 64, 0, stream>>>(dst1, dst2, off, ucnt);

  scan1_k<<<SCAN_BLOCKS, 256, 0, stream>>>(ucnt, uoff, bs, NB);
  scan2_k<<<1, 512, 0, stream>>>(bs, SCAN_BLOCKS);
  scan3_k<<<SCAN_BLOCKS, 256, 0, stream>>>(uoff, ucnt, bs, NB);

  fill_k<<<4096, 256, 0, stream>>>((int*)d_out, out_size);
  outscatter_k<<<NB, 64, 0, stream>>>(dst1, off, uoff, ucnt, (int*)d_out, oute);
}

// Round 3
// 194.779 us; speedup vs baseline: 3.7431x; 3.7431x over previous
//
#include <hip/hip_runtime.h>
#include <stdint.h>

#define BUK 782        // ceil(100000 / 128) src buckets
#define CAP 7808       // per-bucket region capacity (mean ~6246 + ~20 sigma)
#define CH  8192       // edges per passA block
#define EPT 16         // CH / 512 threads

__device__ __forceinline__ uint32_t rotl32(uint32_t x, int r) { return (x << r) | (x >> (32 - r)); }

// JAX threefry2x32, key=(0,42), counts x=(0,i); partitionable bits = out0^out1  (validated absmax=0)
__device__ __forceinline__ uint32_t threefry_bits(uint32_t i) {
  const uint32_t k0 = 0u, k1 = 42u;
  const uint32_t k2 = k0 ^ k1 ^ 0x1BD11BDAu;
  uint32_t x0 = k0;
  uint32_t x1 = i + k1;
#define TF_R(r) { x0 += x1; x1 = rotl32(x1, r); x1 ^= x0; }
  TF_R(13) TF_R(15) TF_R(26) TF_R(6)   x0 += k1; x1 += k2 + 1u;
  TF_R(17) TF_R(29) TF_R(16) TF_R(24)  x0 += k2; x1 += k0 + 2u;
  TF_R(13) TF_R(15) TF_R(26) TF_R(6)   x0 += k0; x1 += k1 + 3u;
  TF_R(17) TF_R(29) TF_R(16) TF_R(24)  x0 += k1; x1 += k2 + 4u;
  TF_R(13) TF_R(15) TF_R(26) TF_R(6)   x0 += k2; x1 += k0 + 5u;
#undef TF_R
  return x0 ^ x1;
}

__device__ __forceinline__ bool keep_edge(uint32_t i, float kp) {
  uint32_t bits = threefry_bits(i);
  float u = __uint_as_float((bits >> 9) | 0x3f800000u) - 1.0f;
  return u < kp;
}

__device__ __forceinline__ float keep_prob(const float* pp) {
  double pd = (double)pp[0];
  return (float)(1.0 / (1.0 + exp(-pd)));
}

// ---- pass A: keep-mask + LDS bucket-sort of 8192-edge chunks + coalesced bucket flush ----
__global__ __launch_bounds__(512) void passA_k(const int* __restrict__ a0,
                                               const int* __restrict__ an,
                                               int e0, int en, const float* __restrict__ pp,
                                               uint32_t* __restrict__ cur_g,
                                               uint32_t* __restrict__ bkt) {
  __shared__ uint32_t stageK[CH];     // 32 KB: bucket-sorted key24s
  __shared__ uint16_t stageB[CH];     // 16 KB: bucket id per staged element
  __shared__ uint32_t cntA[784];      // per-bucket counts (padded)
  __shared__ uint32_t loA[784];       // exclusive prefix (local)
  __shared__ uint32_t gb[784];        // cursor during scatter, then global base
  __shared__ uint32_t sums[512];      // pair-sum scan workspace

  float kp = keep_prob(pp);
  int tid = threadIdx.x;
  int total = e0 + en;
  int base = blockIdx.x * CH;

  uint32_t key[EPT];
  uint32_t bkid[EPT];

  for (int t = tid; t < 784; t += 512) cntA[t] = 0;
  __syncthreads();

  // phase 1: load, keep-mask, key, LDS histogram
#pragma unroll
  for (int k = 0; k < EPT; k++) {
    int idx = base + k * 512 + tid;
    uint32_t ky = 0xFFFFFFFFu, b_ = 0xFFFFFFFFu;
    if (idx < total) {
      int s, d;
      bool keep = true;
      if (idx < e0) {
        keep = keep_edge((uint32_t)idx, kp);
        s = a0[idx];
        d = a0[e0 + idx];
      } else {
        int j = idx - e0;
        s = an[j];
        d = an[en + j];
      }
      if (keep) {
        uint32_t us = (uint32_t)s;
        b_ = us >> 7;
        if (b_ < BUK) {
          ky = ((us & 127u) << 17) | (uint32_t)d;
        } else {
          b_ = 0xFFFFFFFFu;  // impossible by construction; drop safely
        }
      }
    }
    key[k] = ky;
    bkid[k] = b_;
    if (b_ != 0xFFFFFFFFu) atomicAdd(&cntA[b_], 1u);
  }
  __syncthreads();

  // phase 2: exclusive scan over 784 bins (pairs of 2 -> 392 sums, Hillis over 512)
  {
    uint32_t s2 = 0;
    if (tid < 392) s2 = cntA[2 * tid] + cntA[2 * tid + 1];
    sums[tid] = s2;
    __syncthreads();
    for (int off = 1; off < 512; off <<= 1) {
      uint32_t a = (tid >= off) ? sums[tid - off] : 0u;
      __syncthreads();
      sums[tid] += a;
      __syncthreads();
    }
    if (tid < 392) {
      uint32_t b0 = sums[tid] - s2;
      loA[2 * tid] = b0;
      loA[2 * tid + 1] = b0 + cntA[2 * tid];
    }
  }
  __syncthreads();
  for (int t = tid; t < 784; t += 512) gb[t] = loA[t];  // cursors
  __syncthreads();

  // phase 3: LDS counting-scatter into bucket-sorted staging
#pragma unroll
  for (int k = 0; k < EPT; k++) {
    uint32_t b_ = bkid[k];
    if (b_ != 0xFFFFFFFFu) {
      uint32_t p = atomicAdd(&gb[b_], 1u);
      stageK[p] = key[k];
      stageB[p] = (uint16_t)b_;
    }
  }
  __syncthreads();

  // phase 4: one global atomic reservation per present bucket
  for (int t = tid; t < BUK; t += 512) {
    uint32_t c = gb[t] - loA[t];
    gb[t] = c ? atomicAdd(&cur_g[t], c) : 0u;
  }
  __syncthreads();

  // phase 5: flush staged (bucket-contiguous) runs to global bucket regions
  uint32_t kept = sums[511];
  for (uint32_t i = tid; i < kept; i += 512) {
    uint32_t b_ = stageB[i];
    uint32_t addr = gb[b_] + (i - loA[b_]);
    if (addr < CAP) bkt[(size_t)b_ * CAP + addr] = stageK[i];
  }
}

// ---- pass B: per-bucket in-LDS sort (counting by src_low7 + rank by dst) + dedup-compact ----
__global__ __launch_bounds__(512) void passB_k(uint32_t* __restrict__ bkt,
                                               const uint32_t* __restrict__ cur_g,
                                               uint32_t* __restrict__ ucnt) {
  __shared__ uint32_t lin[CAP];
  __shared__ uint32_t lsort[CAP];
  __shared__ uint32_t c128[128], lo128[128], cur128[128];
  __shared__ uint32_t wsum[8];
  __shared__ uint32_t runbase;

  int b = blockIdx.x, tid = threadIdx.x;
  int wid = tid >> 6, lane = tid & 63;
  uint32_t len = cur_g[b];
  if (len > CAP) len = CAP;  // never in practice
  uint32_t* seg = bkt + (size_t)b * CAP;

  if (tid < 128) c128[tid] = 0;
  __syncthreads();
  for (uint32_t i = tid; i < len; i += 512) {
    uint32_t v = seg[i];
    lin[i] = v;
    atomicAdd(&c128[v >> 17], 1u);
  }
  __syncthreads();

  // scan 128 sub-bin counts
  if (tid < 128) lo128[tid] = c128[tid];
  __syncthreads();
  for (int off = 1; off < 128; off <<= 1) {
    uint32_t a = 0;
    if (tid < 128 && tid >= off) a = lo128[tid - off];
    __syncthreads();
    if (tid < 128) lo128[tid] += a;
    __syncthreads();
  }
  if (tid < 128) {
    uint32_t ex = lo128[tid] - c128[tid];
    lo128[tid] = ex;
    cur128[tid] = ex;
  }
  __syncthreads();

  // counting-scatter into sub-bin segments
  for (uint32_t i = tid; i < len; i += 512) {
    uint32_t v = lin[i];
    uint32_t p = atomicAdd(&cur128[v >> 17], 1u);
    lsort[p] = v;
  }
  __syncthreads();

  // per-sub-bin rank sort (one wave per sub-bin; uniform LDS reads = broadcast)
  for (int s = wid; s < 128; s += 8) {
    uint32_t L = c128[s], sb = lo128[s];
    for (uint32_t i0 = lane; i0 < L; i0 += 64) {
      uint32_t x = lsort[sb + i0];
      uint32_t pos = 0;
      for (uint32_t j = 0; j < L; j++) {
        uint32_t y = lsort[sb + j];
        pos += (y < x || (y == x && j < i0)) ? 1u : 0u;
      }
      lin[sb + pos] = x;
    }
  }
  __syncthreads();

  // dedup-compact lin -> seg (in place), block ballots
  if (tid == 0) runbase = 0;
  __syncthreads();
  for (uint32_t base3 = 0; base3 < len; base3 += 512) {
    uint32_t i = base3 + tid;
    bool valid = i < len;
    uint32_t x = valid ? lin[i] : 0u;
    bool uniq = valid && (i == 0 || lin[i - 1] != x);
    unsigned long long ball = __ballot(uniq ? 1 : 0);
    if (lane == 0) wsum[wid] = (uint32_t)__popcll(ball);
    __syncthreads();
    uint32_t wb = 0, tile = 0;
    for (int w = 0; w < 8; w++) {
      uint32_t c = wsum[w];
      if (w < wid) wb += c;
      tile += c;
    }
    uint32_t r = runbase + wb + (uint32_t)__popcll(ball & ((1ull << lane) - 1ull));
    if (uniq) seg[r] = x;
    __syncthreads();
    if (tid == 0) runbase += tile;
    __syncthreads();
  }
  if (tid == 0) ucnt[b] = runbase;
}

// ---- single-block exclusive scan over 782 unique counts ----
__global__ __launch_bounds__(1024) void uscan_k(const uint32_t* __restrict__ ucnt,
                                                uint32_t* __restrict__ uoff) {
  __shared__ uint32_t s[1024];
  int t = threadIdx.x;
  uint32_t v = (t < BUK) ? ucnt[t] : 0u;
  s[t] = v;
  __syncthreads();
  for (int off = 1; off < 1024; off <<= 1) {
    uint32_t a = (t >= off) ? s[t - off] : 0u;
    __syncthreads();
    s[t] += a;
    __syncthreads();
  }
  if (t <= BUK) uoff[t] = s[t] - v;  // t==BUK: total (v==0)
}

// ---- pass C: expand deduped keys to the two output rows ----
__global__ __launch_bounds__(256) void passC_k(const uint32_t* __restrict__ bkt,
                                               const uint32_t* __restrict__ uoff,
                                               int* __restrict__ out, int oute) {
  int b = blockIdx.x;
  uint32_t lo = uoff[b], u = uoff[b + 1] - lo;
  const uint32_t* seg = bkt + (size_t)b * CAP;
  for (uint32_t k = threadIdx.x; k < u; k += 256) {
    uint32_t key = seg[k];
    out[lo + k] = (int)((uint32_t)(b << 7) | (key >> 17));
    out[oute + lo + k] = (int)(key & 0x1FFFFu);
  }
}

// ---- fill only the invalid tail with -1 ----
__global__ void tail_k(const uint32_t* __restrict__ uoff, int* __restrict__ out, int oute) {
  uint32_t total = uoff[BUK];
  for (uint32_t i = blockIdx.x * blockDim.x + threadIdx.x + total; i < (uint32_t)oute;
       i += gridDim.x * blockDim.x) {
    out[i] = -1;
    out[oute + i] = -1;
  }
}

extern "C" void kernel_launch(void* const* d_in, const int* in_sizes, int n_in,
                              void* d_out, int out_size, void* d_ws, size_t ws_size,
                              hipStream_t stream) {
  const int* a0 = (const int*)d_in[0];
  const int* an = (const int*)d_in[1];
  const float* pp = (const float*)d_in[3];
  int e0 = in_sizes[0] / 2;
  int en = in_sizes[1] / 2;
  int M = e0 + en;
  int oute = out_size / 2;

  uint8_t* wbase = (uint8_t*)d_ws;
  size_t o = 0;
  auto nxt = [&](size_t bytes) -> void* {
    void* p = wbase + o;
    o = (o + bytes + 255) & ~(size_t)255;
    return p;
  };
  uint32_t* cur_g = (uint32_t*)nxt((size_t)BUK * 4);
  uint32_t* ucnt  = (uint32_t*)nxt((size_t)BUK * 4);
  uint32_t* uoff  = (uint32_t*)nxt((size_t)(BUK + 1) * 4);
  uint32_t* bkt   = (uint32_t*)nxt((size_t)BUK * CAP * 4);  // ~24.4 MB

  int ablocks = (M + CH - 1) / CH;  // 782

  hipMemsetAsync(cur_g, 0, (size_t)BUK * 4, stream);
  passA_k<<<ablocks, 512, 0, stream>>>(a0, an, e0, en, pp, cur_g, bkt);
  passB_k<<<BUK, 512, 0, stream>>>(bkt, cur_g, ucnt);
  uscan_k<<<1, 1024, 0, stream>>>(ucnt, uoff);
  passC_k<<<BUK, 256, 0, stream>>>(bkt, uoff, (int*)d_out, oute);
  tail_k<<<1024, 256, 0, stream>>>(uoff, (int*)d_out, oute);
}

// Round 4
// 130.642 us; speedup vs baseline: 5.5806x; 1.4909x over previous
//
#include <hip/hip_runtime.h>
#include <stdint.h>

#define BUK 782        // ceil(100000 / 128) src buckets
#define CAP 6912       // per-bucket region capacity (mean ~6246, sigma ~79 -> +8.4 sigma)
#define CH  8192       // edges per passA block
#define EPT 16         // CH / 512 threads
#define SENTK 0xFFFFFFFFu

__device__ __forceinline__ uint32_t rotl32(uint32_t x, int r) { return (x << r) | (x >> (32 - r)); }

// JAX threefry2x32, key=(0,42), counts x=(0,i); partitionable bits = out0^out1  (validated absmax=0)
__device__ __forceinline__ uint32_t threefry_bits(uint32_t i) {
  const uint32_t k0 = 0u, k1 = 42u;
  const uint32_t k2 = k0 ^ k1 ^ 0x1BD11BDAu;
  uint32_t x0 = k0;
  uint32_t x1 = i + k1;
#define TF_R(r) { x0 += x1; x1 = rotl32(x1, r); x1 ^= x0; }
  TF_R(13) TF_R(15) TF_R(26) TF_R(6)   x0 += k1; x1 += k2 + 1u;
  TF_R(17) TF_R(29) TF_R(16) TF_R(24)  x0 += k2; x1 += k0 + 2u;
  TF_R(13) TF_R(15) TF_R(26) TF_R(6)   x0 += k0; x1 += k1 + 3u;
  TF_R(17) TF_R(29) TF_R(16) TF_R(24)  x0 += k1; x1 += k2 + 4u;
  TF_R(13) TF_R(15) TF_R(26) TF_R(6)   x0 += k2; x1 += k0 + 5u;
#undef TF_R
  return x0 ^ x1;
}

__device__ __forceinline__ bool keep_edge(uint32_t i, float kp) {
  uint32_t bits = threefry_bits(i);
  float u = __uint_as_float((bits >> 9) | 0x3f800000u) - 1.0f;
  return u < kp;
}

__device__ __forceinline__ float keep_prob(const float* pp) {
  double pd = (double)pp[0];
  return (float)(1.0 / (1.0 + exp(-pd)));
}

// ---- pass A: keep-mask + LDS bucket-sort of 8192-edge chunks + coalesced bucket flush ----
__global__ __launch_bounds__(512) void passA_k(const int* __restrict__ a0,
                                               const int* __restrict__ an,
                                               int e0, int en, const float* __restrict__ pp,
                                               uint32_t* __restrict__ cur_g,
                                               uint32_t* __restrict__ bkt) {
  __shared__ uint32_t stageK[CH];     // 32 KB: bucket-sorted key24s
  __shared__ uint16_t stageB[CH];     // 16 KB: bucket id per staged element
  __shared__ uint32_t cntA[784];      // per-bucket counts (padded)
  __shared__ uint32_t loA[784];       // exclusive prefix (local)
  __shared__ uint32_t gb[784];        // cursor during scatter, then global base
  __shared__ uint32_t sums[512];      // pair-sum scan workspace

  float kp = keep_prob(pp);
  int tid = threadIdx.x;
  int total = e0 + en;
  int base = blockIdx.x * CH;

  uint32_t key[EPT];
  uint32_t bkid[EPT];

  for (int t = tid; t < 784; t += 512) cntA[t] = 0;
  __syncthreads();

#pragma unroll
  for (int k = 0; k < EPT; k++) {
    int idx = base + k * 512 + tid;
    uint32_t ky = SENTK, b_ = SENTK;
    if (idx < total) {
      int s, d;
      bool keep = true;
      if (idx < e0) {
        keep = keep_edge((uint32_t)idx, kp);
        s = a0[idx];
        d = a0[e0 + idx];
      } else {
        int j = idx - e0;
        s = an[j];
        d = an[en + j];
      }
      if (keep) {
        uint32_t us = (uint32_t)s;
        b_ = us >> 7;
        if (b_ < BUK) {
          ky = ((us & 127u) << 17) | (uint32_t)d;
        } else {
          b_ = SENTK;
        }
      }
    }
    key[k] = ky;
    bkid[k] = b_;
    if (b_ != SENTK) atomicAdd(&cntA[b_], 1u);
  }
  __syncthreads();

  // exclusive scan over 784 bins (pairs -> 392 sums, Hillis over 512)
  {
    uint32_t s2 = 0;
    if (tid < 392) s2 = cntA[2 * tid] + cntA[2 * tid + 1];
    sums[tid] = s2;
    __syncthreads();
    for (int off = 1; off < 512; off <<= 1) {
      uint32_t a = (tid >= off) ? sums[tid - off] : 0u;
      __syncthreads();
      sums[tid] += a;
      __syncthreads();
    }
    if (tid < 392) {
      uint32_t b0 = sums[tid] - s2;
      loA[2 * tid] = b0;
      loA[2 * tid + 1] = b0 + cntA[2 * tid];
    }
  }
  __syncthreads();
  for (int t = tid; t < 784; t += 512) gb[t] = loA[t];
  __syncthreads();

#pragma unroll
  for (int k = 0; k < EPT; k++) {
    uint32_t b_ = bkid[k];
    if (b_ != SENTK) {
      uint32_t p = atomicAdd(&gb[b_], 1u);
      stageK[p] = key[k];
      stageB[p] = (uint16_t)b_;
    }
  }
  __syncthreads();

  for (int t = tid; t < BUK; t += 512) {
    uint32_t c = gb[t] - loA[t];
    gb[t] = c ? atomicAdd(&cur_g[t], c) : 0u;
  }
  __syncthreads();

  uint32_t kept = sums[511];
  for (uint32_t i = tid; i < kept; i += 512) {
    uint32_t b_ = stageB[i];
    uint32_t addr = gb[b_] + (i - loA[b_]);
    if (addr < CAP) bkt[(size_t)b_ * CAP + addr] = stageK[i];
  }
}

// ---- pass B v2: group by src in LDS, register-bitonic sort per sub-bin, dedup-compact ----
__global__ __launch_bounds__(512) void passB_k(uint32_t* __restrict__ bkt,
                                               const uint32_t* __restrict__ cur_g,
                                               uint32_t* __restrict__ ucnt) {
  __shared__ uint32_t lin[CAP];                       // 27 KB
  __shared__ uint32_t c128[128], lo128[128], cur128[128];
  __shared__ uint32_t wsum[8];
  __shared__ uint32_t runbase;

  int b = blockIdx.x, tid = threadIdx.x;
  int wid = tid >> 6, lane = tid & 63;
  uint32_t len = cur_g[b];
  if (len > CAP) len = CAP;
  uint32_t* seg = bkt + (size_t)b * CAP;

  if (tid < 128) c128[tid] = 0;
  __syncthreads();

  // histogram by src_low7 (global read #1, coalesced)
  for (uint32_t i = tid; i < len; i += 512) atomicAdd(&c128[seg[i] >> 17], 1u);
  __syncthreads();

  // scan 128 sub-bin counts
  if (tid < 128) lo128[tid] = c128[tid];
  __syncthreads();
  for (int off = 1; off < 128; off <<= 1) {
    uint32_t a = 0;
    if (tid < 128 && tid >= off) a = lo128[tid - off];
    __syncthreads();
    if (tid < 128) lo128[tid] += a;
    __syncthreads();
  }
  if (tid < 128) {
    uint32_t ex = lo128[tid] - c128[tid];
    lo128[tid] = ex;
    cur128[tid] = ex;
  }
  __syncthreads();

  // counting-scatter into sub-bin segments (global read #2: L2-resident)
  for (uint32_t i = tid; i < len; i += 512) {
    uint32_t v = seg[i];
    uint32_t p = atomicAdd(&cur128[v >> 17], 1u);
    lin[p] = v;
  }
  __syncthreads();

  // per-sub-bin register bitonic sort (one wave per sub-bin, round-robin)
  for (int s = wid; s < 128; s += 8) {
    uint32_t L = c128[s], sb = lo128[s];
    if (L <= 1u) continue;
    if (L <= 64u) {
      uint32_t v = (lane < (int)L) ? lin[sb + lane] : SENTK;
#pragma unroll
      for (int k = 2; k <= 64; k <<= 1) {
#pragma unroll
        for (int j = k >> 1; j >= 1; j >>= 1) {
          uint32_t o = __shfl_xor(v, j, 64);
          bool takeMin = (((lane & j) == 0) == ((lane & k) == 0));
          uint32_t mn = v < o ? v : o, mx = v < o ? o : v;
          v = takeMin ? mn : mx;
        }
      }
      if (lane < (int)L) lin[sb + lane] = v;
    } else if (L <= 128u) {
      // 128-element bitonic: element e0=lane in v0, e1=64+lane in v1
      uint32_t v0 = (lane < (int)L) ? lin[sb + lane] : SENTK;
      uint32_t v1 = (64 + lane < (int)L) ? lin[sb + 64 + lane] : SENTK;
#pragma unroll
      for (int k = 2; k <= 64; k <<= 1) {
#pragma unroll
        for (int j = k >> 1; j >= 1; j >>= 1) {
          uint32_t o0 = __shfl_xor(v0, j, 64);
          uint32_t o1 = __shfl_xor(v1, j, 64);
          bool lower = ((lane & j) == 0);
          bool up0 = ((lane & k) == 0);
          bool up1 = (k == 64) ? false : up0;  // e1&64 = 64 -> descending half
          uint32_t mn0 = v0 < o0 ? v0 : o0, mx0 = v0 < o0 ? o0 : v0;
          uint32_t mn1 = v1 < o1 ? v1 : o1, mx1 = v1 < o1 ? o1 : v1;
          v0 = (lower == up0) ? mn0 : mx0;
          v1 = (lower == up1) ? mn1 : mx1;
        }
      }
      // k=128 merge: j=64 is the cross-register exchange (ascending everywhere)
      {
        uint32_t lo = v0 < v1 ? v0 : v1, hi = v0 < v1 ? v1 : v0;
        v0 = lo; v1 = hi;
#pragma unroll
        for (int j = 32; j >= 1; j >>= 1) {
          uint32_t o0 = __shfl_xor(v0, j, 64);
          uint32_t o1 = __shfl_xor(v1, j, 64);
          bool lower = ((lane & j) == 0);
          uint32_t mn0 = v0 < o0 ? v0 : o0, mx0 = v0 < o0 ? o0 : v0;
          uint32_t mn1 = v1 < o1 ? v1 : o1, mx1 = v1 < o1 ? o1 : v1;
          v0 = lower ? mn0 : mx0;
          v1 = lower ? mn1 : mx1;
        }
      }
      if (lane < (int)L) lin[sb + lane] = v0;
      if (64 + lane < (int)L) lin[sb + 64 + lane] = v1;
    } else {
      // L > 128: never expected (mean 48.8, +11 sigma). Rank-sort via dead global seg.
      uint32_t* gsc = seg + sb;
      for (uint32_t i0 = lane; i0 < L; i0 += 64) {
        uint32_t x = lin[sb + i0];
        uint32_t pos = 0;
        for (uint32_t j = 0; j < L; j++) {
          uint32_t y = lin[sb + j];
          pos += (y < x || (y == x && j < i0)) ? 1u : 0u;
        }
        gsc[pos] = x;
      }
      asm volatile("s_waitcnt vmcnt(0)" ::: "memory");
      for (uint32_t i0 = lane; i0 < L; i0 += 64) lin[sb + i0] = gsc[i0];
    }
  }
  __syncthreads();

  // dedup-compact lin -> seg front (keys fully sorted: src_low7 in high bits)
  if (tid == 0) runbase = 0;
  __syncthreads();
  for (uint32_t base3 = 0; base3 < len; base3 += 512) {
    uint32_t i = base3 + tid;
    bool valid = i < len;
    uint32_t x = valid ? lin[i] : 0u;
    bool uniq = valid && (i == 0 || lin[i - 1] != x);
    unsigned long long ball = __ballot(uniq ? 1 : 0);
    if (lane == 0) wsum[wid] = (uint32_t)__popcll(ball);
    __syncthreads();
    uint32_t wb = 0, tile = 0;
    for (int w = 0; w < 8; w++) {
      uint32_t c = wsum[w];
      if (w < wid) wb += c;
      tile += c;
    }
    uint32_t r = runbase + wb + (uint32_t)__popcll(ball & ((1ull << lane) - 1ull));
    if (uniq) seg[r] = x;
    __syncthreads();
    if (tid == 0) runbase += tile;
    __syncthreads();
  }
  if (tid == 0) ucnt[b] = runbase;
}

// ---- single-block exclusive scan over 782 unique counts ----
__global__ __launch_bounds__(1024) void uscan_k(const uint32_t* __restrict__ ucnt,
                                                uint32_t* __restrict__ uoff) {
  __shared__ uint32_t s[1024];
  int t = threadIdx.x;
  uint32_t v = (t < BUK) ? ucnt[t] : 0u;
  s[t] = v;
  __syncthreads();
  for (int off = 1; off < 1024; off <<= 1) {
    uint32_t a = (t >= off) ? s[t - off] : 0u;
    __syncthreads();
    s[t] += a;
    __syncthreads();
  }
  if (t <= BUK) uoff[t] = s[t] - v;
}

// ---- pass C: expand deduped keys to the two output rows ----
__global__ __launch_bounds__(256) void passC_k(const uint32_t* __restrict__ bkt,
                                               const uint32_t* __restrict__ uoff,
                                               int* __restrict__ out, int oute) {
  int b = blockIdx.x;
  uint32_t lo = uoff[b], u = uoff[b + 1] - lo;
  const uint32_t* seg = bkt + (size_t)b * CAP;
  for (uint32_t k = threadIdx.x; k < u; k += 256) {
    uint32_t key = seg[k];
    out[lo + k] = (int)((uint32_t)(b << 7) | (key >> 17));
    out[oute + lo + k] = (int)(key & 0x1FFFFu);
  }
}

// ---- fill only the invalid tail with -1 ----
__global__ void tail_k(const uint32_t* __restrict__ uoff, int* __restrict__ out, int oute) {
  uint32_t total = uoff[BUK];
  for (uint32_t i = blockIdx.x * blockDim.x + threadIdx.x + total; i < (uint32_t)oute;
       i += gridDim.x * blockDim.x) {
    out[i] = -1;
    out[oute + i] = -1;
  }
}

extern "C" void kernel_launch(void* const* d_in, const int* in_sizes, int n_in,
                              void* d_out, int out_size, void* d_ws, size_t ws_size,
                              hipStream_t stream) {
  const int* a0 = (const int*)d_in[0];
  const int* an = (const int*)d_in[1];
  const float* pp = (const float*)d_in[3];
  int e0 = in_sizes[0] / 2;
  int en = in_sizes[1] / 2;
  int M = e0 + en;
  int oute = out_size / 2;

  uint8_t* wbase = (uint8_t*)d_ws;
  size_t o = 0;
  auto nxt = [&](size_t bytes) -> void* {
    void* p = wbase + o;
    o = (o + bytes + 255) & ~(size_t)255;
    return p;
  };
  uint32_t* cur_g = (uint32_t*)nxt((size_t)BUK * 4);
  uint32_t* ucnt  = (uint32_t*)nxt((size_t)BUK * 4);
  uint32_t* uoff  = (uint32_t*)nxt((size_t)(BUK + 1) * 4);
  uint32_t* bkt   = (uint32_t*)nxt((size_t)BUK * CAP * 4);  // ~21.6 MB

  int ablocks = (M + CH - 1) / CH;  // 782

  hipMemsetAsync(cur_g, 0, (size_t)BUK * 4, stream);
  passA_k<<<ablocks, 512, 0, stream>>>(a0, an, e0, en, pp, cur_g, bkt);
  passB_k<<<BUK, 512, 0, stream>>>(bkt, cur_g, ucnt);
  uscan_k<<<1, 1024, 0, stream>>>(ucnt, uoff);
  passC_k<<<BUK, 256, 0, stream>>>(bkt, uoff, (int*)d_out, oute);
  tail_k<<<1024, 256, 0, stream>>>(uoff, (int*)d_out, oute);
}

// Round 6
// 117.244 us; speedup vs baseline: 6.2184x; 1.1143x over previous
//
#include <hip/hip_runtime.h>
#include <stdint.h>

#define BUK 782        // ceil(100000 / 128) src buckets
#define CAP 6912       // per-bucket region capacity (mean ~6246)
#define CH  8192       // edges per passA block
#define EPT 16         // CH / 512 threads
#define SENTK 0xFFFFFFFFu

__device__ __forceinline__ uint32_t rotl32(uint32_t x, int r) { return (x << r) | (x >> (32 - r)); }

// JAX threefry2x32, key=(0,42), counts x=(0,i); partitionable bits = out0^out1  (validated absmax=0)
__device__ __forceinline__ uint32_t threefry_bits(uint32_t i) {
  const uint32_t k0 = 0u, k1 = 42u;
  const uint32_t k2 = k0 ^ k1 ^ 0x1BD11BDAu;
  uint32_t x0 = k0;
  uint32_t x1 = i + k1;
#define TF_R(r) { x0 += x1; x1 = rotl32(x1, r); x1 ^= x0; }
  TF_R(13) TF_R(15) TF_R(26) TF_R(6)   x0 += k1; x1 += k2 + 1u;
  TF_R(17) TF_R(29) TF_R(16) TF_R(24)  x0 += k2; x1 += k0 + 2u;
  TF_R(13) TF_R(15) TF_R(26) TF_R(6)   x0 += k0; x1 += k1 + 3u;
  TF_R(17) TF_R(29) TF_R(16) TF_R(24)  x0 += k1; x1 += k2 + 4u;
  TF_R(13) TF_R(15) TF_R(26) TF_R(6)   x0 += k2; x1 += k0 + 5u;
#undef TF_R
  return x0 ^ x1;
}

__device__ __forceinline__ bool keep_edge(uint32_t i, float kp) {
  uint32_t bits = threefry_bits(i);
  float u = __uint_as_float((bits >> 9) | 0x3f800000u) - 1.0f;
  return u < kp;
}

__device__ __forceinline__ float keep_prob(const float* pp) {
  double pd = (double)pp[0];
  return (float)(1.0 / (1.0 + exp(-pd)));
}

// ---- VALU-pipe xor-shuffle: DPP for j<16, ds for 16/32 ----
template <int J>
__device__ __forceinline__ uint32_t xshf(uint32_t v, int lane) {
  if constexpr (J == 1) {
    return (uint32_t)__builtin_amdgcn_mov_dpp((int)v, 0xB1, 0xF, 0xF, true);  // quad_perm(1,0,3,2)
  } else if constexpr (J == 2) {
    return (uint32_t)__builtin_amdgcn_mov_dpp((int)v, 0x4E, 0xF, 0xF, true);  // quad_perm(2,3,0,1)
  } else if constexpr (J == 4 || J == 8) {
    // row_shl:J (0x100|J): lane i <- i+J ; row_shr:J (0x110|J): lane i <- i-J (rocPRIM scan idiom)
    uint32_t up = (uint32_t)__builtin_amdgcn_mov_dpp((int)v, 0x100 | J, 0xF, 0xF, true);
    uint32_t dn = (uint32_t)__builtin_amdgcn_mov_dpp((int)v, 0x110 | J, 0xF, 0xF, true);
    return (lane & J) ? dn : up;
  } else {
    return (uint32_t)__shfl_xor((int)v, J, 64);
  }
}

__device__ __forceinline__ void cex(uint32_t& v, uint32_t o, bool takeMin) {
  uint32_t mn = v < o ? v : o, mx = v < o ? o : v;
  v = takeMin ? mn : mx;
}
template <int J>
__device__ __forceinline__ void ce1(uint32_t& v, bool takeMin, int lane) {
  cex(v, xshf<J>(v, lane), takeMin);
}

__device__ __forceinline__ uint32_t bitonic64(uint32_t v, int lane) {
#define BS1(J, K) ce1<J>(v, ((lane & (J)) == 0) == ((lane & (K)) == 0), lane)
  BS1(1, 2);
  BS1(2, 4); BS1(1, 4);
  BS1(4, 8); BS1(2, 8); BS1(1, 8);
  BS1(8, 16); BS1(4, 16); BS1(2, 16); BS1(1, 16);
  BS1(16, 32); BS1(8, 32); BS1(4, 32); BS1(2, 32); BS1(1, 32);
  // k=64: ascending
  ce1<32>(v, (lane & 32) == 0, lane); ce1<16>(v, (lane & 16) == 0, lane);
  ce1<8>(v, (lane & 8) == 0, lane);   ce1<4>(v, (lane & 4) == 0, lane);
  ce1<2>(v, (lane & 2) == 0, lane);   ce1<1>(v, (lane & 1) == 0, lane);
#undef BS1
  return v;
}

__device__ __forceinline__ void bitonic128(uint32_t& v0, uint32_t& v1, int lane) {
#define BS2(J, K) { bool tm = ((lane & (J)) == 0) == ((lane & (K)) == 0); ce1<J>(v0, tm, lane); ce1<J>(v1, tm, lane); }
  BS2(1, 2);
  BS2(2, 4); BS2(1, 4);
  BS2(4, 8); BS2(2, 8); BS2(1, 8);
  BS2(8, 16); BS2(4, 16); BS2(2, 16); BS2(1, 16);
  BS2(16, 32); BS2(8, 32); BS2(4, 32); BS2(2, 32); BS2(1, 32);
#undef BS2
  // k=64: v0 (elems 0..63) ascending, v1 (elems 64..127) descending
  ce1<32>(v0, (lane & 32) == 0, lane); ce1<32>(v1, (lane & 32) != 0, lane);
  ce1<16>(v0, (lane & 16) == 0, lane); ce1<16>(v1, (lane & 16) != 0, lane);
  ce1<8>(v0, (lane & 8) == 0, lane);   ce1<8>(v1, (lane & 8) != 0, lane);
  ce1<4>(v0, (lane & 4) == 0, lane);   ce1<4>(v1, (lane & 4) != 0, lane);
  ce1<2>(v0, (lane & 2) == 0, lane);   ce1<2>(v1, (lane & 2) != 0, lane);
  ce1<1>(v0, (lane & 1) == 0, lane);   ce1<1>(v1, (lane & 1) != 0, lane);
  // k=128: j=64 cross-register, then j=32..1 ascending everywhere
  { uint32_t lo = v0 < v1 ? v0 : v1, hi = v0 < v1 ? v1 : v0; v0 = lo; v1 = hi; }
  ce1<32>(v0, (lane & 32) == 0, lane); ce1<32>(v1, (lane & 32) == 0, lane);
  ce1<16>(v0, (lane & 16) == 0, lane); ce1<16>(v1, (lane & 16) == 0, lane);
  ce1<8>(v0, (lane & 8) == 0, lane);   ce1<8>(v1, (lane & 8) == 0, lane);
  ce1<4>(v0, (lane & 4) == 0, lane);   ce1<4>(v1, (lane & 4) == 0, lane);
  ce1<2>(v0, (lane & 2) == 0, lane);   ce1<2>(v1, (lane & 2) == 0, lane);
  ce1<1>(v0, (lane & 1) == 0, lane);   ce1<1>(v1, (lane & 1) == 0, lane);
}

// ---- pass A: keep-mask + LDS bucket-sort of 8192-edge chunks + coalesced bucket flush ----
__global__ __launch_bounds__(512) void passA_k(const int* __restrict__ a0,
                                               const int* __restrict__ an,
                                               int e0, int en, const float* __restrict__ pp,
                                               uint32_t* __restrict__ cur_g,
                                               uint32_t* __restrict__ bkt) {
  __shared__ uint32_t stageK[CH];
  __shared__ uint16_t stageB[CH];
  __shared__ uint32_t cntA[784];
  __shared__ uint32_t loA[784];
  __shared__ uint32_t gb[784];
  __shared__ uint32_t sums[512];

  float kp = keep_prob(pp);
  int tid = threadIdx.x;
  int total = e0 + en;
  int base = blockIdx.x * CH;

  uint32_t key[EPT];
  uint32_t bkid[EPT];

  for (int t = tid; t < 784; t += 512) cntA[t] = 0;
  __syncthreads();

#pragma unroll
  for (int k = 0; k < EPT; k++) {
    int idx = base + k * 512 + tid;
    uint32_t ky = SENTK, b_ = SENTK;
    if (idx < total) {
      int s, d;
      bool keep = true;
      if (idx < e0) {
        keep = keep_edge((uint32_t)idx, kp);
        s = a0[idx];
        d = a0[e0 + idx];
      } else {
        int j = idx - e0;
        s = an[j];
        d = an[en + j];
      }
      if (keep) {
        uint32_t us = (uint32_t)s;
        b_ = us >> 7;
        if (b_ < BUK) {
          ky = ((us & 127u) << 17) | (uint32_t)d;
        } else {
          b_ = SENTK;
        }
      }
    }
    key[k] = ky;
    bkid[k] = b_;
    if (b_ != SENTK) atomicAdd(&cntA[b_], 1u);
  }
  __syncthreads();

  {
    uint32_t s2 = 0;
    if (tid < 392) s2 = cntA[2 * tid] + cntA[2 * tid + 1];
    sums[tid] = s2;
    __syncthreads();
    for (int off = 1; off < 512; off <<= 1) {
      uint32_t a = (tid >= off) ? sums[tid - off] : 0u;
      __syncthreads();
      sums[tid] += a;
      __syncthreads();
    }
    if (tid < 392) {
      uint32_t b0 = sums[tid] - s2;
      loA[2 * tid] = b0;
      loA[2 * tid + 1] = b0 + cntA[2 * tid];
    }
  }
  __syncthreads();
  for (int t = tid; t < 784; t += 512) gb[t] = loA[t];
  __syncthreads();

#pragma unroll
  for (int k = 0; k < EPT; k++) {
    uint32_t b_ = bkid[k];
    if (b_ != SENTK) {
      uint32_t p = atomicAdd(&gb[b_], 1u);
      stageK[p] = key[k];
      stageB[p] = (uint16_t)b_;
    }
  }
  __syncthreads();

  for (int t = tid; t < BUK; t += 512) {
    uint32_t c = gb[t] - loA[t];
    gb[t] = c ? atomicAdd(&cur_g[t], c) : 0u;
  }
  __syncthreads();

  uint32_t kept = sums[511];
  for (uint32_t i = tid; i < kept; i += 512) {
    uint32_t b_ = stageB[i];
    uint32_t addr = gb[b_] + (i - loA[b_]);
    if (addr < CAP) bkt[(size_t)b_ * CAP + addr] = stageK[i];
  }
}

// ---- pass B v3: group by src, DPP-bitonic per sub-bin, per-wave ballot dedup ----
__global__ __launch_bounds__(512) void passB_k(uint32_t* __restrict__ bkt,
                                               const uint32_t* __restrict__ cur_g,
                                               uint32_t* __restrict__ ucnt) {
  __shared__ uint32_t lin[CAP];                 // 27 KB
  __shared__ uint32_t c128[128], lo128[128], cur128[128];
  __shared__ uint32_t u128[128], uo128[128];

  int b = blockIdx.x, tid = threadIdx.x;
  int wid = tid >> 6, lane = tid & 63;
  uint32_t len = cur_g[b];
  if (len > CAP) len = CAP;
  uint32_t* seg = bkt + (size_t)b * CAP;

  if (tid < 128) c128[tid] = 0;
  __syncthreads();
  for (uint32_t i = tid; i < len; i += 512) atomicAdd(&c128[seg[i] >> 17], 1u);
  __syncthreads();

  if (tid < 128) lo128[tid] = c128[tid];
  __syncthreads();
  for (int off = 1; off < 128; off <<= 1) {
    uint32_t a = 0;
    if (tid < 128 && tid >= off) a = lo128[tid - off];
    __syncthreads();
    if (tid < 128) lo128[tid] += a;
    __syncthreads();
  }
  if (tid < 128) {
    uint32_t ex = lo128[tid] - c128[tid];
    lo128[tid] = ex;
    cur128[tid] = ex;
  }
  __syncthreads();

  for (uint32_t i = tid; i < len; i += 512) {
    uint32_t v = seg[i];
    lin[atomicAdd(&cur128[v >> 17], 1u)] = v;
  }
  __syncthreads();

  // per-wave sub-bin sort + dedup-compact (regions disjoint across waves)
  for (int s = wid; s < 128; s += 8) {
    uint32_t L = c128[s], sb = lo128[s];
    if (L > 1u && L <= 64u) {
      uint32_t v = (lane < (int)L) ? lin[sb + lane] : SENTK;
      v = bitonic64(v, lane);
      if (lane < (int)L) lin[sb + lane] = v;
    } else if (L > 64u && L <= 128u) {
      uint32_t v0 = (lane < (int)L) ? lin[sb + lane] : SENTK;
      uint32_t v1 = (64 + lane < (int)L) ? lin[sb + 64 + lane] : SENTK;
      bitonic128(v0, v1, lane);
      if (lane < (int)L) lin[sb + lane] = v0;
      if (64 + lane < (int)L) lin[sb + 64 + lane] = v1;
    } else if (L > 128u) {
      // never expected (mean 48.8); rank-sort via dead global seg region
      uint32_t* gsc = seg + sb;
      for (uint32_t i0 = lane; i0 < L; i0 += 64) {
        uint32_t x = lin[sb + i0];
        uint32_t pos = 0;
        for (uint32_t j = 0; j < L; j++) {
          uint32_t y = lin[sb + j];
          pos += (y < x || (y == x && j < i0)) ? 1u : 0u;
        }
        gsc[pos] = x;
      }
      asm volatile("s_waitcnt vmcnt(0)" ::: "memory");
      for (uint32_t i0 = lane; i0 < L; i0 += 64) lin[sb + i0] = gsc[i0];
    }
    // dedup-compact within sub-bin (generic 64-wide tiles, in place)
    uint32_t ub = 0;
    for (uint32_t t = 0; t < L; t += 64) {
      uint32_t i = t + lane;
      bool valid = i < L;
      uint32_t x = valid ? lin[sb + i] : 0u;
      uint32_t prev = valid ? lin[sb + (i == 0 ? 0 : i - 1)] : 0u;
      bool uniq = valid && (i == 0 || prev != x);
      unsigned long long ball = __ballot(uniq ? 1 : 0);
      uint32_t rank = (uint32_t)__popcll(ball & ((1ull << lane) - 1ull));
      if (uniq) lin[sb + ub + rank] = x;
      ub += (uint32_t)__popcll(ball);
    }
    if (lane == 0) u128[s] = ub;
  }
  __syncthreads();

  // scan unique counts -> uo128 (exclusive)
  if (tid < 128) uo128[tid] = u128[tid];
  __syncthreads();
  for (int off = 1; off < 128; off <<= 1) {
    uint32_t a = 0;
    if (tid < 128 && tid >= off) a = uo128[tid - off];
    __syncthreads();
    if (tid < 128) uo128[tid] += a;
    __syncthreads();
  }
  if (tid < 128) uo128[tid] -= u128[tid];
  __syncthreads();

  // copy compacted uniques to seg front (sorted: sub-bin order = key order)
  for (int s = wid; s < 128; s += 8) {
    uint32_t u = u128[s], sb = lo128[s], ob = uo128[s];
    for (uint32_t k2 = lane; k2 < u; k2 += 64) seg[ob + k2] = lin[sb + k2];
  }
  if (tid == 0) ucnt[b] = uo128[127] + u128[127];
}

// ---- single-block exclusive scan over 782 unique counts ----
__global__ __launch_bounds__(1024) void uscan_k(const uint32_t* __restrict__ ucnt,
                                                uint32_t* __restrict__ uoff) {
  __shared__ uint32_t s[1024];
  int t = threadIdx.x;
  uint32_t v = (t < BUK) ? ucnt[t] : 0u;
  s[t] = v;
  __syncthreads();
  for (int off = 1; off < 1024; off <<= 1) {
    uint32_t a = (t >= off) ? s[t - off] : 0u;
    __syncthreads();
    s[t] += a;
    __syncthreads();
  }
  if (t <= BUK) uoff[t] = s[t] - v;
}

// ---- pass C: expand deduped keys to the two output rows ----
__global__ __launch_bounds__(256) void passC_k(const uint32_t* __restrict__ bkt,
                                               const uint32_t* __restrict__ uoff,
                                               int* __restrict__ out, int oute) {
  int b = blockIdx.x;
  uint32_t lo = uoff[b], u = uoff[b + 1] - lo;
  const uint32_t* seg = bkt + (size_t)b * CAP;
  for (uint32_t k = threadIdx.x; k < u; k += 256) {
    uint32_t key = seg[k];
    out[lo + k] = (int)((uint32_t)(b << 7) | (key >> 17));
    out[oute + lo + k] = (int)(key & 0x1FFFFu);
  }
}

// ---- fill only the invalid tail with -1 ----
__global__ void tail_k(const uint32_t* __restrict__ uoff, int* __restrict__ out, int oute) {
  uint32_t total = uoff[BUK];
  for (uint32_t i = blockIdx.x * blockDim.x + threadIdx.x + total; i < (uint32_t)oute;
       i += gridDim.x * blockDim.x) {
    out[i] = -1;
    out[oute + i] = -1;
  }
}

extern "C" void kernel_launch(void* const* d_in, const int* in_sizes, int n_in,
                              void* d_out, int out_size, void* d_ws, size_t ws_size,
                              hipStream_t stream) {
  const int* a0 = (const int*)d_in[0];
  const int* an = (const int*)d_in[1];
  const float* pp = (const float*)d_in[3];
  int e0 = in_sizes[0] / 2;
  int en = in_sizes[1] / 2;
  int M = e0 + en;
  int oute = out_size / 2;

  uint8_t* wbase = (uint8_t*)d_ws;
  size_t o = 0;
  auto nxt = [&](size_t bytes) -> void* {
    void* p = wbase + o;
    o = (o + bytes + 255) & ~(size_t)255;
    return p;
  };
  uint32_t* cur_g = (uint32_t*)nxt((size_t)BUK * 4);
  uint32_t* ucnt  = (uint32_t*)nxt((size_t)BUK * 4);
  uint32_t* uoff  = (uint32_t*)nxt((size_t)(BUK + 1) * 4);
  uint32_t* bkt   = (uint32_t*)nxt((size_t)BUK * CAP * 4);  // ~21.6 MB

  int ablocks = (M + CH - 1) / CH;  // 782

  hipMemsetAsync(cur_g, 0, (size_t)BUK * 4, stream);
  passA_k<<<ablocks, 512, 0, stream>>>(a0, an, e0, en, pp, cur_g, bkt);
  passB_k<<<BUK, 512, 0, stream>>>(bkt, cur_g, ucnt);
  uscan_k<<<1, 1024, 0, stream>>>(ucnt, uoff);
  passC_k<<<BUK, 256, 0, stream>>>(bkt, uoff, (int*)d_out, oute);
  tail_k<<<1024, 256, 0, stream>>>(uoff, (int*)d_out, oute);
}

// Round 7
// 112.441 us; speedup vs baseline: 6.4840x; 1.0427x over previous
//
#include <hip/hip_runtime.h>
#include <stdint.h>

#define BUK 782        // ceil(100000 / 128) src buckets
#define CAP 6912       // per-bucket region capacity (mean ~6246)
#define CH  8192       // edges per passA block
#define SENTK 0xFFFFFFFFu

__device__ __forceinline__ uint32_t rotl32(uint32_t x, int r) { return (x << r) | (x >> (32 - r)); }

// JAX threefry2x32, key=(0,42), counts x=(0,i); partitionable bits = out0^out1  (validated absmax=0)
__device__ __forceinline__ uint32_t threefry_bits(uint32_t i) {
  const uint32_t k0 = 0u, k1 = 42u;
  const uint32_t k2 = k0 ^ k1 ^ 0x1BD11BDAu;
  uint32_t x0 = k0;
  uint32_t x1 = i + k1;
#define TF_R(r) { x0 += x1; x1 = rotl32(x1, r); x1 ^= x0; }
  TF_R(13) TF_R(15) TF_R(26) TF_R(6)   x0 += k1; x1 += k2 + 1u;
  TF_R(17) TF_R(29) TF_R(16) TF_R(24)  x0 += k2; x1 += k0 + 2u;
  TF_R(13) TF_R(15) TF_R(26) TF_R(6)   x0 += k0; x1 += k1 + 3u;
  TF_R(17) TF_R(29) TF_R(16) TF_R(24)  x0 += k1; x1 += k2 + 4u;
  TF_R(13) TF_R(15) TF_R(26) TF_R(6)   x0 += k2; x1 += k0 + 5u;
#undef TF_R
  return x0 ^ x1;
}

__device__ __forceinline__ bool keep_edge(uint32_t i, float kp) {
  uint32_t bits = threefry_bits(i);
  float u = __uint_as_float((bits >> 9) | 0x3f800000u) - 1.0f;
  return u < kp;
}

__device__ __forceinline__ float keep_prob(const float* pp) {
  double pd = (double)pp[0];
  return (float)(1.0 / (1.0 + exp(-pd)));
}

// ---- VALU-pipe xor-shuffle: DPP for j<16, ds for 16/32 ----
template <int J>
__device__ __forceinline__ uint32_t xshf(uint32_t v, int lane) {
  if constexpr (J == 1) {
    return (uint32_t)__builtin_amdgcn_mov_dpp((int)v, 0xB1, 0xF, 0xF, true);  // quad_perm(1,0,3,2)
  } else if constexpr (J == 2) {
    return (uint32_t)__builtin_amdgcn_mov_dpp((int)v, 0x4E, 0xF, 0xF, true);  // quad_perm(2,3,0,1)
  } else if constexpr (J == 4 || J == 8) {
    uint32_t up = (uint32_t)__builtin_amdgcn_mov_dpp((int)v, 0x100 | J, 0xF, 0xF, true);
    uint32_t dn = (uint32_t)__builtin_amdgcn_mov_dpp((int)v, 0x110 | J, 0xF, 0xF, true);
    return (lane & J) ? dn : up;
  } else {
    return (uint32_t)__shfl_xor((int)v, J, 64);
  }
}

__device__ __forceinline__ void cex(uint32_t& v, uint32_t o, bool takeMin) {
  uint32_t mn = v < o ? v : o, mx = v < o ? o : v;
  v = takeMin ? mn : mx;
}
template <int J>
__device__ __forceinline__ void ce1(uint32_t& v, bool takeMin, int lane) {
  cex(v, xshf<J>(v, lane), takeMin);
}

__device__ __forceinline__ uint32_t bitonic64(uint32_t v, int lane) {
#define BS1(J, K) ce1<J>(v, ((lane & (J)) == 0) == ((lane & (K)) == 0), lane)
  BS1(1, 2);
  BS1(2, 4); BS1(1, 4);
  BS1(4, 8); BS1(2, 8); BS1(1, 8);
  BS1(8, 16); BS1(4, 16); BS1(2, 16); BS1(1, 16);
  BS1(16, 32); BS1(8, 32); BS1(4, 32); BS1(2, 32); BS1(1, 32);
  ce1<32>(v, (lane & 32) == 0, lane); ce1<16>(v, (lane & 16) == 0, lane);
  ce1<8>(v, (lane & 8) == 0, lane);   ce1<4>(v, (lane & 4) == 0, lane);
  ce1<2>(v, (lane & 2) == 0, lane);   ce1<1>(v, (lane & 1) == 0, lane);
#undef BS1
  return v;
}

__device__ __forceinline__ void bitonic128(uint32_t& v0, uint32_t& v1, int lane) {
#define BS2(J, K) { bool tm = ((lane & (J)) == 0) == ((lane & (K)) == 0); ce1<J>(v0, tm, lane); ce1<J>(v1, tm, lane); }
  BS2(1, 2);
  BS2(2, 4); BS2(1, 4);
  BS2(4, 8); BS2(2, 8); BS2(1, 8);
  BS2(8, 16); BS2(4, 16); BS2(2, 16); BS2(1, 16);
  BS2(16, 32); BS2(8, 32); BS2(4, 32); BS2(2, 32); BS2(1, 32);
#undef BS2
  ce1<32>(v0, (lane & 32) == 0, lane); ce1<32>(v1, (lane & 32) != 0, lane);
  ce1<16>(v0, (lane & 16) == 0, lane); ce1<16>(v1, (lane & 16) != 0, lane);
  ce1<8>(v0, (lane & 8) == 0, lane);   ce1<8>(v1, (lane & 8) != 0, lane);
  ce1<4>(v0, (lane & 4) == 0, lane);   ce1<4>(v1, (lane & 4) != 0, lane);
  ce1<2>(v0, (lane & 2) == 0, lane);   ce1<2>(v1, (lane & 2) != 0, lane);
  ce1<1>(v0, (lane & 1) == 0, lane);   ce1<1>(v1, (lane & 1) != 0, lane);
  { uint32_t lo = v0 < v1 ? v0 : v1, hi = v0 < v1 ? v1 : v0; v0 = lo; v1 = hi; }
  ce1<32>(v0, (lane & 32) == 0, lane); ce1<32>(v1, (lane & 32) == 0, lane);
  ce1<16>(v0, (lane & 16) == 0, lane); ce1<16>(v1, (lane & 16) == 0, lane);
  ce1<8>(v0, (lane & 8) == 0, lane);   ce1<8>(v1, (lane & 8) == 0, lane);
  ce1<4>(v0, (lane & 4) == 0, lane);   ce1<4>(v1, (lane & 4) == 0, lane);
  ce1<2>(v0, (lane & 2) == 0, lane);   ce1<2>(v1, (lane & 2) == 0, lane);
  ce1<1>(v0, (lane & 1) == 0, lane);   ce1<1>(v1, (lane & 1) == 0, lane);
}

// ---- pass A v2: int4-vectorized keep-mask + LDS bucket-sort + coalesced bucket flush ----
__global__ __launch_bounds__(512) void passA_k(const int* __restrict__ a0,
                                               const int* __restrict__ an,
                                               int e0, int en, const float* __restrict__ pp,
                                               uint32_t* __restrict__ cur_g,
                                               uint32_t* __restrict__ bkt) {
  __shared__ uint32_t stageK[CH];
  __shared__ uint16_t stageB[CH];
  __shared__ uint32_t cntA[784];
  __shared__ uint32_t loA[784];
  __shared__ uint32_t gb[784];
  __shared__ uint32_t sums[512];

  float kp = keep_prob(pp);
  int tid = threadIdx.x;
  int total = e0 + en;
  int base = blockIdx.x * CH;

  uint32_t key[16];
  uint32_t bkid[16];

  for (int t = tid; t < 784; t += 512) cntA[t] = 0;
  __syncthreads();

  // phase 1: 4 groups of 4 consecutive edges per thread, int4 loads
#pragma unroll
  for (int k = 0; k < 4; k++) {
    int g = base + 4 * (k * 512 + tid);  // first edge of this group (16B aligned)
    int s4[4], d4[4];
    bool have = false;
    if (g + 3 < e0) {                     // fully in A0
      int4 sv = *reinterpret_cast<const int4*>(&a0[g]);
      int4 dv = *reinterpret_cast<const int4*>(&a0[e0 + g]);
      s4[0] = sv.x; s4[1] = sv.y; s4[2] = sv.z; s4[3] = sv.w;
      d4[0] = dv.x; d4[1] = dv.y; d4[2] = dv.z; d4[3] = dv.w;
      have = true;
    } else if (g >= e0 && g + 3 < total) { // fully in An
      int j = g - e0;
      int4 sv = *reinterpret_cast<const int4*>(&an[j]);
      int4 dv = *reinterpret_cast<const int4*>(&an[en + j]);
      s4[0] = sv.x; s4[1] = sv.y; s4[2] = sv.z; s4[3] = sv.w;
      d4[0] = dv.x; d4[1] = dv.y; d4[2] = dv.z; d4[3] = dv.w;
      have = true;
    } else if (g < total) {                // straddle (1 group per grid) / tail
      for (int e = 0; e < 4; e++) {
        int idx = g + e;
        if (idx < total) {
          if (idx < e0) { s4[e] = a0[idx]; d4[e] = a0[e0 + idx]; }
          else          { int j = idx - e0; s4[e] = an[j]; d4[e] = an[en + j]; }
        } else { s4[e] = -1; d4[e] = 0; }
      }
      have = true;
    }
#pragma unroll
    for (int e = 0; e < 4; e++) {
      int idx = g + e;
      uint32_t ky = SENTK, b_ = SENTK;
      if (have && idx < total && s4[e] >= 0) {
        bool keep = (idx < e0) ? keep_edge((uint32_t)idx, kp) : true;
        if (keep) {
          uint32_t us = (uint32_t)s4[e];
          b_ = us >> 7;
          if (b_ < BUK) ky = ((us & 127u) << 17) | (uint32_t)d4[e];
          else b_ = SENTK;
        }
      }
      key[k * 4 + e] = ky;
      bkid[k * 4 + e] = b_;
      if (b_ != SENTK) atomicAdd(&cntA[b_], 1u);
    }
  }
  __syncthreads();

  // exclusive scan over 784 bins (pairs -> 392 sums, Hillis over 512)
  {
    uint32_t s2 = 0;
    if (tid < 392) s2 = cntA[2 * tid] + cntA[2 * tid + 1];
    sums[tid] = s2;
    __syncthreads();
    for (int off = 1; off < 512; off <<= 1) {
      uint32_t a = (tid >= off) ? sums[tid - off] : 0u;
      __syncthreads();
      sums[tid] += a;
      __syncthreads();
    }
    if (tid < 392) {
      uint32_t b0 = sums[tid] - s2;
      loA[2 * tid] = b0;
      loA[2 * tid + 1] = b0 + cntA[2 * tid];
    }
  }
  __syncthreads();
  for (int t = tid; t < 784; t += 512) gb[t] = loA[t];
  __syncthreads();

#pragma unroll
  for (int k = 0; k < 16; k++) {
    uint32_t b_ = bkid[k];
    if (b_ != SENTK) {
      uint32_t p = atomicAdd(&gb[b_], 1u);
      stageK[p] = key[k];
      stageB[p] = (uint16_t)b_;
    }
  }
  __syncthreads();

  for (int t = tid; t < BUK; t += 512) {
    uint32_t c = gb[t] - loA[t];
    gb[t] = c ? atomicAdd(&cur_g[t], c) : 0u;
  }
  __syncthreads();

  uint32_t kept = sums[511];
  for (uint32_t i = tid; i < kept; i += 512) {
    uint32_t b_ = stageB[i];
    uint32_t addr = gb[b_] + (i - loA[b_]);
    if (addr < CAP) bkt[(size_t)b_ * CAP + addr] = stageK[i];
  }
}

// ---- pass B v4: single uint4 read -> registers; hist+scatter from regs; DPP-bitonic; dedup ----
__global__ __launch_bounds__(512) void passB_k(uint32_t* __restrict__ bkt,
                                               const uint32_t* __restrict__ cur_g,
                                               uint32_t* __restrict__ ucnt) {
  __shared__ uint32_t lin[CAP];                 // 27 KB
  __shared__ uint32_t c128[128], lo128[128], cur128[128];
  __shared__ uint32_t u128[128], uo128[128];

  int b = blockIdx.x, tid = threadIdx.x;
  int wid = tid >> 6, lane = tid & 63;
  uint32_t len = cur_g[b];
  if (len > CAP) len = CAP;
  uint32_t* seg = bkt + (size_t)b * CAP;

  if (tid < 128) c128[tid] = 0;
  __syncthreads();

  // single vectorized read into registers (<= 16 values/thread)
  uint32_t rv[16];
#pragma unroll
  for (int k = 0; k < 4; k++) {
    uint32_t i4 = 4u * (uint32_t)(k * 512 + tid);
    if (i4 + 3 < len) {
      uint4 v = *reinterpret_cast<const uint4*>(&seg[i4]);
      rv[4 * k] = v.x; rv[4 * k + 1] = v.y; rv[4 * k + 2] = v.z; rv[4 * k + 3] = v.w;
    } else {
#pragma unroll
      for (int e = 0; e < 4; e++) rv[4 * k + e] = (i4 + e < len) ? seg[i4 + e] : SENTK;
    }
  }

  // histogram from registers
#pragma unroll
  for (int k = 0; k < 16; k++)
    if (rv[k] != SENTK) atomicAdd(&c128[rv[k] >> 17], 1u);
  __syncthreads();

  // scan 128 sub-bin counts
  if (tid < 128) lo128[tid] = c128[tid];
  __syncthreads();
  for (int off = 1; off < 128; off <<= 1) {
    uint32_t a = 0;
    if (tid < 128 && tid >= off) a = lo128[tid - off];
    __syncthreads();
    if (tid < 128) lo128[tid] += a;
    __syncthreads();
  }
  if (tid < 128) {
    uint32_t ex = lo128[tid] - c128[tid];
    lo128[tid] = ex;
    cur128[tid] = ex;
  }
  __syncthreads();

  // counting-scatter from registers
#pragma unroll
  for (int k = 0; k < 16; k++)
    if (rv[k] != SENTK) lin[atomicAdd(&cur128[rv[k] >> 17], 1u)] = rv[k];
  __syncthreads();

  // per-wave sub-bin sort + dedup-compact (regions disjoint across waves)
  for (int s = wid; s < 128; s += 8) {
    uint32_t L = c128[s], sb = lo128[s];
    if (L > 1u && L <= 64u) {
      uint32_t v = (lane < (int)L) ? lin[sb + lane] : SENTK;
      v = bitonic64(v, lane);
      if (lane < (int)L) lin[sb + lane] = v;
    } else if (L > 64u && L <= 128u) {
      uint32_t v0 = (lane < (int)L) ? lin[sb + lane] : SENTK;
      uint32_t v1 = (64 + lane < (int)L) ? lin[sb + 64 + lane] : SENTK;
      bitonic128(v0, v1, lane);
      if (lane < (int)L) lin[sb + lane] = v0;
      if (64 + lane < (int)L) lin[sb + 64 + lane] = v1;
    } else if (L > 128u) {
      // never expected (mean 48.8); rank-sort via dead global seg region
      uint32_t* gsc = seg + sb;
      for (uint32_t i0 = lane; i0 < L; i0 += 64) {
        uint32_t x = lin[sb + i0];
        uint32_t pos = 0;
        for (uint32_t j = 0; j < L; j++) {
          uint32_t y = lin[sb + j];
          pos += (y < x || (y == x && j < i0)) ? 1u : 0u;
        }
        gsc[pos] = x;
      }
      asm volatile("s_waitcnt vmcnt(0)" ::: "memory");
      for (uint32_t i0 = lane; i0 < L; i0 += 64) lin[sb + i0] = gsc[i0];
    }
    // dedup-compact within sub-bin
    uint32_t ub = 0;
    for (uint32_t t = 0; t < L; t += 64) {
      uint32_t i = t + lane;
      bool valid = i < L;
      uint32_t x = valid ? lin[sb + i] : 0u;
      uint32_t prev = valid ? lin[sb + (i == 0 ? 0 : i - 1)] : 0u;
      bool uniq = valid && (i == 0 || prev != x);
      unsigned long long ball = __ballot(uniq ? 1 : 0);
      uint32_t rank = (uint32_t)__popcll(ball & ((1ull << lane) - 1ull));
      if (uniq) lin[sb + ub + rank] = x;
      ub += (uint32_t)__popcll(ball);
    }
    if (lane == 0) u128[s] = ub;
  }
  __syncthreads();

  // scan unique counts -> uo128 (exclusive)
  if (tid < 128) uo128[tid] = u128[tid];
  __syncthreads();
  for (int off = 1; off < 128; off <<= 1) {
    uint32_t a = 0;
    if (tid < 128 && tid >= off) a = uo128[tid - off];
    __syncthreads();
    if (tid < 128) uo128[tid] += a;
    __syncthreads();
  }
  if (tid < 128) uo128[tid] -= u128[tid];
  __syncthreads();

  // copy compacted uniques to seg front (sub-bin order = key order)
  for (int s = wid; s < 128; s += 8) {
    uint32_t u = u128[s], sb = lo128[s], ob = uo128[s];
    for (uint32_t k2 = lane; k2 < u; k2 += 64) seg[ob + k2] = lin[sb + k2];
  }
  if (tid == 0) ucnt[b] = uo128[127] + u128[127];
}

// ---- single-block exclusive scan over 782 unique counts ----
__global__ __launch_bounds__(1024) void uscan_k(const uint32_t* __restrict__ ucnt,
                                                uint32_t* __restrict__ uoff) {
  __shared__ uint32_t s[1024];
  int t = threadIdx.x;
  uint32_t v = (t < BUK) ? ucnt[t] : 0u;
  s[t] = v;
  __syncthreads();
  for (int off = 1; off < 1024; off <<= 1) {
    uint32_t a = (t >= off) ? s[t - off] : 0u;
    __syncthreads();
    s[t] += a;
    __syncthreads();
  }
  if (t <= BUK) uoff[t] = s[t] - v;
}

// ---- pass C: expand deduped keys to the two output rows ----
__global__ __launch_bounds__(256) void passC_k(const uint32_t* __restrict__ bkt,
                                               const uint32_t* __restrict__ uoff,
                                               int* __restrict__ out, int oute) {
  int b = blockIdx.x;
  uint32_t lo = uoff[b], u = uoff[b + 1] - lo;
  const uint32_t* seg = bkt + (size_t)b * CAP;
  for (uint32_t k = threadIdx.x; k < u; k += 256) {
    uint32_t key = seg[k];
    out[lo + k] = (int)((uint32_t)(b << 7) | (key >> 17));
    out[oute + lo + k] = (int)(key & 0x1FFFFu);
  }
}

// ---- fill only the invalid tail with -1 ----
__global__ void tail_k(const uint32_t* __restrict__ uoff, int* __restrict__ out, int oute) {
  uint32_t total = uoff[BUK];
  for (uint32_t i = blockIdx.x * blockDim.x + threadIdx.x + total; i < (uint32_t)oute;
       i += gridDim.x * blockDim.x) {
    out[i] = -1;
    out[oute + i] = -1;
  }
}

extern "C" void kernel_launch(void* const* d_in, const int* in_sizes, int n_in,
                              void* d_out, int out_size, void* d_ws, size_t ws_size,
                              hipStream_t stream) {
  const int* a0 = (const int*)d_in[0];
  const int* an = (const int*)d_in[1];
  const float* pp = (const float*)d_in[3];
  int e0 = in_sizes[0] / 2;
  int en = in_sizes[1] / 2;
  int M = e0 + en;
  int oute = out_size / 2;

  uint8_t* wbase = (uint8_t*)d_ws;
  size_t o = 0;
  auto nxt = [&](size_t bytes) -> void* {
    void* p = wbase + o;
    o = (o + bytes + 255) & ~(size_t)255;
    return p;
  };
  uint32_t* cur_g = (uint32_t*)nxt((size_t)BUK * 4);
  uint32_t* ucnt  = (uint32_t*)nxt((size_t)BUK * 4);
  uint32_t* uoff  = (uint32_t*)nxt((size_t)(BUK + 1) * 4);
  uint32_t* bkt   = (uint32_t*)nxt((size_t)BUK * CAP * 4);  // ~21.6 MB

  int ablocks = (M + CH - 1) / CH;  // 782

  hipMemsetAsync(cur_g, 0, (size_t)BUK * 4, stream);
  passA_k<<<ablocks, 512, 0, stream>>>(a0, an, e0, en, pp, cur_g, bkt);
  passB_k<<<BUK, 512, 0, stream>>>(bkt, cur_g, ucnt);
  uscan_k<<<1, 1024, 0, stream>>>(ucnt, uoff);
  passC_k<<<BUK, 256, 0, stream>>>(bkt, uoff, (int*)d_out, oute);
  tail_k<<<1024, 256, 0, stream>>>(uoff, (int*)d_out, oute);
}